// Round 1
// baseline (144.950 us; speedup 1.0000x reference)
//
#include <hip/hip_runtime.h>
#include <stdint.h>

// HashGridEncoder forward (Instant-NGP style), MI355X / gfx950.
// L=16 levels, T=2^15 entries/level, F=2 features, DIM=3.
// One thread per (point, level): t = n*16 + l.
//   - output store: float2 per thread, consecutive -> perfectly coalesced.
//   - 16 lanes share one point's x -> loads merge in L1.
//   - 8 random float2 gathers/thread from the 256KB per-level table slice
//     (4MB total, L2/L3 resident).

constexpr int      kL = 16;
constexpr int      kT = 32768;            // 2^15
constexpr uint32_t kP1 = 2654435761u;
constexpr uint32_t kP2 = 805459861u;

// scales[l] = 16 * 2^(l/3) - 1, computed in f64 and rounded to f32.
// (B = (512/16)^(1/15) = 2^(1/3) exactly; continuity of the trilinear
// interpolation makes ulp-level differences vs JAX's powf irrelevant.)
__device__ __constant__ float c_scales[kL] = {
    15.0f,
    19.158736798317972f,
    24.398416831491190f,
    31.0f,
    39.317473596635944f,
    49.796833662982380f,
    63.0f,
    79.634947193271890f,
    100.59366732596477f,
    127.0f,
    160.26989438654378f,
    202.18733465192953f,
    255.0f,
    321.53978877308750f,
    405.37466930385903f,
    511.0f
};

__global__ __launch_bounds__(256) void hashgrid_fwd(
    const float*  __restrict__ x,      // (N,3)
    const float2* __restrict__ table,  // (L,T) of float2
    float2*       __restrict__ out,    // (N,L) of float2
    int n_points)
{
    int t = blockIdx.x * 256 + threadIdx.x;
    int n = t >> 4;
    int l = t & 15;
    if (n >= n_points) return;

    float x0 = x[n * 3 + 0];
    float x1 = x[n * 3 + 1];
    float x2 = x[n * 3 + 2];

    float s  = c_scales[l];
    // xn = (x+1)/2 ; pos = xn*s + 0.5
    float p0 = fmaf((x0 + 1.0f) * 0.5f, s, 0.5f);
    float p1 = fmaf((x1 + 1.0f) * 0.5f, s, 0.5f);
    float p2 = fmaf((x2 + 1.0f) * 0.5f, s, 0.5f);

    float fl0 = floorf(p0), fl1 = floorf(p1), fl2 = floorf(p2);
    float fr0 = p0 - fl0,   fr1 = p1 - fl1,   fr2 = p2 - fl2;

    uint32_t g0 = (uint32_t)(int)fl0;
    uint32_t g1 = (uint32_t)(int)fl1;
    uint32_t g2 = (uint32_t)(int)fl2;

    // per-axis hash contributions for corner bit 0/1
    uint32_t hx0 = g0;        uint32_t hx1 = g0 + 1u;
    uint32_t hy0 = g1 * kP1;  uint32_t hy1 = hy0 + kP1;
    uint32_t hz0 = g2 * kP2;  uint32_t hz1 = hz0 + kP2;

    float w0 = 1.0f - fr0, w1 = 1.0f - fr1, w2 = 1.0f - fr2;

    const float2* tab = table + (size_t)l * kT;

    float acc_x = 0.0f, acc_y = 0.0f;
#pragma unroll
    for (int c = 0; c < 8; ++c) {
        uint32_t h = ((c & 1) ? hx1 : hx0)
                   ^ ((c & 2) ? hy1 : hy0)
                   ^ ((c & 4) ? hz1 : hz0);
        uint32_t idx = h & (uint32_t)(kT - 1);
        float2 f = tab[idx];
        float w = ((c & 1) ? fr0 : w0)
                * ((c & 2) ? fr1 : w1)
                * ((c & 4) ? fr2 : w2);
        acc_x = fmaf(w, f.x, acc_x);
        acc_y = fmaf(w, f.y, acc_y);
    }

    out[t] = make_float2(acc_x, acc_y);
}

extern "C" void kernel_launch(void* const* d_in, const int* in_sizes, int n_in,
                              void* d_out, int out_size, void* d_ws, size_t ws_size,
                              hipStream_t stream) {
    const float*  x     = (const float*)d_in[0];
    const float2* table = (const float2*)d_in[1];
    float2*       out   = (float2*)d_out;

    int n_points = in_sizes[0] / 3;           // (N,3) flat
    int total    = n_points * kL;             // one thread per (point, level)
    int blocks   = (total + 255) / 256;

    hashgrid_fwd<<<blocks, 256, 0, stream>>>(x, table, out, n_points);
}

// Round 3
// 139.675 us; speedup vs baseline: 1.0378x; 1.0378x over previous
//
#include <hip/hip_runtime.h>
#include <stdint.h>

// HashGridEncoder forward (Instant-NGP style), MI355X / gfx950.
// L=16 levels, T=2^15 entries/level, F=2 features, DIM=3.
// One thread per (point, level): t = n*16 + l.
// Round-2/3 change: PRIMES[0]==1, so when g0 is even the two x-corners of a
// cell hash to an aligned index pair {i, i^1} -> fetch both with ONE
// global_load_dwordx4. Cuts gather requests from 8 to 6 per thread (avg).
// Output stores are nontemporal (native ext_vector float2 — HIP's float2
// class is rejected by the builtin) so the 64MB write stream doesn't evict
// the 4MB table from the per-XCD L2s.

constexpr int      kL = 16;
constexpr int      kT = 32768;            // 2^15
constexpr uint32_t kM = kT - 1;
constexpr uint32_t kP1 = 2654435761u;
constexpr uint32_t kP2 = 805459861u;

typedef float f32x2 __attribute__((ext_vector_type(2)));

// scales[l] = 16 * 2^(l/3) - 1  (B = 2^(1/3) exactly), f64-rounded to f32.
__device__ __constant__ float c_scales[kL] = {
    15.0f,
    19.158736798317972f,
    24.398416831491190f,
    31.0f,
    39.317473596635944f,
    49.796833662982380f,
    63.0f,
    79.634947193271890f,
    100.59366732596477f,
    127.0f,
    160.26989438654378f,
    202.18733465192953f,
    255.0f,
    321.53978877308750f,
    405.37466930385903f,
    511.0f
};

__global__ __launch_bounds__(256) void hashgrid_fwd(
    const float*  __restrict__ x,      // (N,3)
    const float2* __restrict__ table,  // (L,T) of float2
    f32x2*        __restrict__ out,    // (N,L) of float2
    int n_points)
{
    int t = blockIdx.x * 256 + threadIdx.x;
    int n = t >> 4;
    int l = t & 15;
    if (n >= n_points) return;

    float x0 = x[n * 3 + 0];
    float x1 = x[n * 3 + 1];
    float x2 = x[n * 3 + 2];

    float s  = c_scales[l];
    // xn = (x+1)/2 ; pos = xn*s + 0.5
    float p0 = fmaf((x0 + 1.0f) * 0.5f, s, 0.5f);
    float p1 = fmaf((x1 + 1.0f) * 0.5f, s, 0.5f);
    float p2 = fmaf((x2 + 1.0f) * 0.5f, s, 0.5f);

    float fl0 = floorf(p0), fl1 = floorf(p1), fl2 = floorf(p2);
    float fr0 = p0 - fl0,   fr1 = p1 - fl1,   fr2 = p2 - fl2;

    uint32_t g0 = (uint32_t)(int)fl0;
    uint32_t g1 = (uint32_t)(int)fl1;
    uint32_t g2 = (uint32_t)(int)fl2;

    uint32_t hy0 = g1 * kP1;  uint32_t hy1 = hy0 + kP1;
    uint32_t hz0 = g2 * kP2;  uint32_t hz1 = hz0 + kP2;

    float wy0 = 1.0f - fr1, wz0 = 1.0f - fr2;
    float wx0 = 1.0f - fr0, wx1 = fr0;

    // 4 (y,z) corner combos: hash xor term and bilinear weight
    uint32_t hyz[4];
    float    wyz[4];
    hyz[0] = hy0 ^ hz0;  wyz[0] = wy0 * wz0;
    hyz[1] = hy1 ^ hz0;  wyz[1] = fr1 * wz0;
    hyz[2] = hy0 ^ hz1;  wyz[2] = wy0 * fr2;
    hyz[3] = hy1 ^ hz1;  wyz[3] = fr1 * fr2;

    const float2* tab = table + (size_t)l * kT;

    float acc_x = 0.0f, acc_y = 0.0f;

    if (!(g0 & 1u)) {
        // even g0: x-corner pair hashes to {i0, i0^1} -> one 16B load
#pragma unroll
        for (int j = 0; j < 4; ++j) {
            uint32_t i0 = (g0 ^ hyz[j]) & kM;
            uint32_t base = i0 & ~1u;
            float4 q = *reinterpret_cast<const float4*>(tab + base);
            bool sw = (i0 & 1u);                 // which half is corner x=0
            float f0x = sw ? q.z : q.x, f0y = sw ? q.w : q.y;
            float f1x = sw ? q.x : q.z, f1y = sw ? q.y : q.w;
            float fx = fmaf(wx0, f0x, wx1 * f1x);
            float fy = fmaf(wx0, f0y, wx1 * f1y);
            acc_x = fmaf(wyz[j], fx, acc_x);
            acc_y = fmaf(wyz[j], fy, acc_y);
        }
    } else {
        // odd g0: corners not adjacent -> two 8B loads
        uint32_t g0p = g0 + 1u;
#pragma unroll
        for (int j = 0; j < 4; ++j) {
            uint32_t i0 = (g0  ^ hyz[j]) & kM;
            uint32_t i1 = (g0p ^ hyz[j]) & kM;
            float2 f0 = tab[i0];
            float2 f1 = tab[i1];
            float fx = fmaf(wx0, f0.x, wx1 * f1.x);
            float fy = fmaf(wx0, f0.y, wx1 * f1.y);
            acc_x = fmaf(wyz[j], fx, acc_x);
            acc_y = fmaf(wyz[j], fy, acc_y);
        }
    }

    f32x2 r; r.x = acc_x; r.y = acc_y;
    __builtin_nontemporal_store(r, &out[t]);
}

extern "C" void kernel_launch(void* const* d_in, const int* in_sizes, int n_in,
                              void* d_out, int out_size, void* d_ws, size_t ws_size,
                              hipStream_t stream) {
    const float*  x     = (const float*)d_in[0];
    const float2* table = (const float2*)d_in[1];
    f32x2*        out   = (f32x2*)d_out;

    int n_points = in_sizes[0] / 3;           // (N,3) flat
    int total    = n_points * kL;             // one thread per (point, level)
    int blocks   = (total + 255) / 256;

    hashgrid_fwd<<<blocks, 256, 0, stream>>>(x, table, out, n_points);
}

// Round 4
// 50.416 us; speedup vs baseline: 2.8751x; 2.7704x over previous
//
#include <hip/hip_runtime.h>
#include <hip/hip_fp16.h>
#include <stdint.h>

// HashGridEncoder forward (Instant-NGP style), MI355X / gfx950.
// L=16 levels, T=2^15 entries/level, F=2 features, DIM=3.
//
// Round-4 restructure: the kernel was bound by unique-L2-line gather traffic
// (~3GB of 64B line fills; instruction merging in round 3 changed nothing).
// Fix: stage each level's 32768-entry table slice in LDS as packed f16x2
// (128KB <= 160KB), so all 64M gathers become LDS reads (no L1/L2 at all).
//   grid = 16 levels x 16 point-chunks, block = 1024 threads, 1 block/CU.
//   bid = l*16 + c  ->  bid%8 == c%8: all 16 level-blocks of a chunk land on
//   the same XCD (round-robin heuristic), so the 16 partial 8B writes to each
//   128B out-line merge in that XCD's L2 before writeback.
// f16 precision: table ~N(0,1e-4); RN error <= |v|*2^-11 ~ 2.4e-7, weights
// sum to 1 -> added output error ~2.4e-7 vs threshold 7.8e-6.

constexpr int      kL  = 16;
constexpr int      kT  = 32768;           // 2^15
constexpr uint32_t kM  = kT - 1;
constexpr uint32_t kP1 = 2654435761u;
constexpr uint32_t kP2 = 805459861u;
constexpr int      kNC = 16;              // point chunks
constexpr int      kBT = 1024;            // threads per block

typedef float f32x2 __attribute__((ext_vector_type(2)));

// scales[l] = 16 * 2^(l/3) - 1  (B = 2^(1/3) exactly), f64-rounded to f32.
__device__ __constant__ float c_scales[kL] = {
    15.0f,
    19.158736798317972f,
    24.398416831491190f,
    31.0f,
    39.317473596635944f,
    49.796833662982380f,
    63.0f,
    79.634947193271890f,
    100.59366732596477f,
    127.0f,
    160.26989438654378f,
    202.18733465192953f,
    255.0f,
    321.53978877308750f,
    405.37466930385903f,
    511.0f
};

__device__ __forceinline__ void unpack_h2(uint32_t u, float& lo, float& hi) {
    __half2 h = *reinterpret_cast<__half2*>(&u);
    lo = __low2float(h);
    hi = __high2float(h);
}

__global__ __launch_bounds__(kBT, 4) void hashgrid_fwd(
    const float*  __restrict__ x,      // (N,3)
    const float2* __restrict__ table,  // (L,T) of float2
    f32x2*        __restrict__ out,    // (N,L) of float2
    int n_points, int chunk_sz)
{
    __shared__ uint32_t ltab[kT];      // 128 KB: level slice as packed f16x2

    int bid = blockIdx.x;
    int l   = bid >> 4;                // bid = l*16 + c  (c fastest -> XCD=c%8)
    int c   = bid & 15;

    // ---- stage level slice: 32768 f32x2 -> packed f16x2 (coalesced) ----
    const float2* tsrc = table + (size_t)l * kT;
    for (int e = threadIdx.x; e < kT; e += kBT) {
        float2 f = tsrc[e];
        uint32_t p = ((uint32_t)__half_as_ushort(__float2half_rn(f.y)) << 16)
                   |  (uint32_t)__half_as_ushort(__float2half_rn(f.x));
        ltab[e] = p;
    }
    __syncthreads();

    float s = c_scales[l];
    int base = c * chunk_sz;
    int lim  = min(base + chunk_sz, n_points);

    for (int n = base + (int)threadIdx.x; n < lim; n += kBT) {
        float x0 = x[n * 3 + 0];
        float x1 = x[n * 3 + 1];
        float x2 = x[n * 3 + 2];

        float p0 = fmaf((x0 + 1.0f) * 0.5f, s, 0.5f);
        float p1 = fmaf((x1 + 1.0f) * 0.5f, s, 0.5f);
        float p2 = fmaf((x2 + 1.0f) * 0.5f, s, 0.5f);

        float fl0 = floorf(p0), fl1 = floorf(p1), fl2 = floorf(p2);
        float fr0 = p0 - fl0,   fr1 = p1 - fl1,   fr2 = p2 - fl2;

        uint32_t g0 = (uint32_t)(int)fl0;
        uint32_t g1 = (uint32_t)(int)fl1;
        uint32_t g2 = (uint32_t)(int)fl2;

        uint32_t hy0 = g1 * kP1;  uint32_t hy1 = hy0 + kP1;
        uint32_t hz0 = g2 * kP2;  uint32_t hz1 = hz0 + kP2;

        float wy0 = 1.0f - fr1, wz0 = 1.0f - fr2;
        float wx0 = 1.0f - fr0, wx1 = fr0;

        uint32_t hyz[4];
        float    wyz[4];
        hyz[0] = hy0 ^ hz0;  wyz[0] = wy0 * wz0;
        hyz[1] = hy1 ^ hz0;  wyz[1] = fr1 * wz0;
        hyz[2] = hy0 ^ hz1;  wyz[2] = wy0 * fr2;
        hyz[3] = hy1 ^ hz1;  wyz[3] = fr1 * fr2;

        float acc_x = 0.0f, acc_y = 0.0f;

        if (!(g0 & 1u)) {
            // even g0: x-corner pair {i0, i0^1} -> one aligned ds_read_b64
#pragma unroll
            for (int j = 0; j < 4; ++j) {
                uint32_t i0 = (g0 ^ hyz[j]) & kM;
                uint32_t pb = i0 & ~1u;
                uint64_t two = *reinterpret_cast<const uint64_t*>(&ltab[pb]);
                uint32_t e0 = (uint32_t)two, e1 = (uint32_t)(two >> 32);
                bool sw = (i0 & 1u);
                uint32_t u0 = sw ? e1 : e0;   // corner x=0
                uint32_t u1 = sw ? e0 : e1;   // corner x=1
                float a0, b0, a1, b1;
                unpack_h2(u0, a0, b0);
                unpack_h2(u1, a1, b1);
                float fx = fmaf(wx0, a0, wx1 * a1);
                float fy = fmaf(wx0, b0, wx1 * b1);
                acc_x = fmaf(wyz[j], fx, acc_x);
                acc_y = fmaf(wyz[j], fy, acc_y);
            }
        } else {
            uint32_t g0p = g0 + 1u;
#pragma unroll
            for (int j = 0; j < 4; ++j) {
                uint32_t i0 = (g0  ^ hyz[j]) & kM;
                uint32_t i1 = (g0p ^ hyz[j]) & kM;
                uint32_t u0 = ltab[i0];
                uint32_t u1 = ltab[i1];
                float a0, b0, a1, b1;
                unpack_h2(u0, a0, b0);
                unpack_h2(u1, a1, b1);
                float fx = fmaf(wx0, a0, wx1 * a1);
                float fy = fmaf(wx0, b0, wx1 * b1);
                acc_x = fmaf(wyz[j], fx, acc_x);
                acc_y = fmaf(wyz[j], fy, acc_y);
            }
        }

        f32x2 r; r.x = acc_x; r.y = acc_y;
        out[(size_t)n * kL + l] = r;   // 8B @128B lane stride; merges in XCD L2
    }
}

extern "C" void kernel_launch(void* const* d_in, const int* in_sizes, int n_in,
                              void* d_out, int out_size, void* d_ws, size_t ws_size,
                              hipStream_t stream) {
    const float*  x     = (const float*)d_in[0];
    const float2* table = (const float2*)d_in[1];
    f32x2*        out   = (f32x2*)d_out;

    int n_points = in_sizes[0] / 3;                  // (N,3) flat
    int chunk_sz = (n_points + kNC - 1) / kNC;       // 31250 for N=500000
    int blocks   = kL * kNC;                         // 256 = 1 per CU

    hashgrid_fwd<<<blocks, kBT, 0, stream>>>(x, table, out, n_points, chunk_sz);
}

// Round 5
// 49.314 us; speedup vs baseline: 2.9393x; 1.0224x over previous
//
#include <hip/hip_runtime.h>
#include <hip/hip_fp16.h>
#include <stdint.h>

// HashGridEncoder forward (Instant-NGP style), MI355X / gfx950.
// L=16 levels, T=2^15 entries/level, F=2 features, DIM=3.
//
// Structure (round 4): one block per (level, point-chunk); level's 32768-entry
// table slice staged in LDS as packed f16x2 (128KB), all gathers are LDS.
// bid = l*16 + c -> bid%8 == c%8: all 16 level-blocks of a chunk share an XCD
// so the 16 partial 8B writes per 128B out-line merge in that XCD's L2
// (WRITE_SIZE confirmed 62.5MB = no amplification).
//
// Round-5 changes:
//  - Removed the per-lane-divergent even/odd g0 branch (parity is random ->
//    waves executed BOTH exec-masked bodies: ~12 LDS ops + 2 interp blocks).
//    Now uniform branchless 8x ds_read_b32 per item.
//  - 2 points per thread per iteration, fully unrolled -> ~16 independent
//    ds_reads in flight to hide LDS latency at the 16-wave/CU occupancy cap.
//  - float4 staging loads.
// f16 precision: table ~N(0,1e-4); RN error <= |v|*2^-11 ~ 2.4e-7, weights
// sum to 1 -> added output error ~2.4e-7 vs threshold 7.8e-6 (absmax 1.9e-6).

constexpr int      kL  = 16;
constexpr int      kT  = 32768;           // 2^15
constexpr uint32_t kM  = kT - 1;
constexpr uint32_t kP1 = 2654435761u;
constexpr uint32_t kP2 = 805459861u;
constexpr int      kNC = 16;              // point chunks
constexpr int      kBT = 1024;            // threads per block

typedef float f32x2 __attribute__((ext_vector_type(2)));

// scales[l] = 16 * 2^(l/3) - 1  (B = 2^(1/3) exactly), f64-rounded to f32.
__device__ __constant__ float c_scales[kL] = {
    15.0f,
    19.158736798317972f,
    24.398416831491190f,
    31.0f,
    39.317473596635944f,
    49.796833662982380f,
    63.0f,
    79.634947193271890f,
    100.59366732596477f,
    127.0f,
    160.26989438654378f,
    202.18733465192953f,
    255.0f,
    321.53978877308750f,
    405.37466930385903f,
    511.0f
};

__global__ __launch_bounds__(kBT, 4) void hashgrid_fwd(
    const float*  __restrict__ x,      // (N,3)
    const float2* __restrict__ table,  // (L,T) of float2
    f32x2*        __restrict__ out,    // (N,L) of float2
    int n_points, int chunk_sz)
{
    __shared__ uint32_t ltab[kT];      // 128 KB: level slice as packed f16x2

    int bid = blockIdx.x;
    int l   = bid >> 4;                // bid = l*16 + c  -> XCD = c%8
    int c   = bid & 15;

    // ---- stage level slice: 32768 f32x2 -> packed f16x2 (float4 loads) ----
    const float4* tsrc4 = reinterpret_cast<const float4*>(table + (size_t)l * kT);
    for (int e = threadIdx.x; e < kT / 2; e += kBT) {
        float4 q = tsrc4[e];
        uint2 pp;
        pp.x = ((uint32_t)__half_as_ushort(__float2half_rn(q.y)) << 16)
             |  (uint32_t)__half_as_ushort(__float2half_rn(q.x));
        pp.y = ((uint32_t)__half_as_ushort(__float2half_rn(q.w)) << 16)
             |  (uint32_t)__half_as_ushort(__float2half_rn(q.z));
        *reinterpret_cast<uint2*>(&ltab[e * 2]) = pp;
    }
    __syncthreads();

    float s = c_scales[l];
    int base = c * chunk_sz;
    int lim  = min(base + chunk_sz, n_points);

    for (int n0 = base + (int)threadIdx.x; n0 < lim; n0 += 2 * kBT) {
        int nn[2];
        nn[0] = n0;
        int nB = n0 + kBT;
        bool hasB = nB < lim;
        nn[1] = hasB ? nB : n0;        // clamp: keep loads in-bounds, skip store

        uint32_t idx[2][8];
        float    w[2][8];

#pragma unroll
        for (int p = 0; p < 2; ++p) {
            int n = nn[p];
            float x0 = x[n * 3 + 0];
            float x1 = x[n * 3 + 1];
            float x2 = x[n * 3 + 2];

            float p0 = fmaf((x0 + 1.0f) * 0.5f, s, 0.5f);
            float p1 = fmaf((x1 + 1.0f) * 0.5f, s, 0.5f);
            float p2 = fmaf((x2 + 1.0f) * 0.5f, s, 0.5f);

            float fl0 = floorf(p0), fl1 = floorf(p1), fl2 = floorf(p2);
            float fr0 = p0 - fl0,   fr1 = p1 - fl1,   fr2 = p2 - fl2;

            uint32_t g0 = (uint32_t)(int)fl0;
            uint32_t g1 = (uint32_t)(int)fl1;
            uint32_t g2 = (uint32_t)(int)fl2;

            uint32_t hx0 = g0;        uint32_t hx1 = g0 + 1u;
            uint32_t hy0 = g1 * kP1;  uint32_t hy1 = hy0 + kP1;
            uint32_t hz0 = g2 * kP2;  uint32_t hz1 = hz0 + kP2;

            float wy0 = 1.0f - fr1, wz0 = 1.0f - fr2;
            float wx0 = 1.0f - fr0;

            float wyz[4];
            wyz[0] = wy0 * wz0;
            wyz[1] = fr1 * wz0;
            wyz[2] = wy0 * fr2;
            wyz[3] = fr1 * fr2;

            uint32_t hyz[4];
            hyz[0] = hy0 ^ hz0;
            hyz[1] = hy1 ^ hz0;
            hyz[2] = hy0 ^ hz1;
            hyz[3] = hy1 ^ hz1;

#pragma unroll
            for (int cc = 0; cc < 8; ++cc) {
                uint32_t hx = (cc & 1) ? hx1 : hx0;
                idx[p][cc] = (hx ^ hyz[cc >> 1]) & kM;
                w[p][cc]   = ((cc & 1) ? fr0 : wx0) * wyz[cc >> 1];
            }
        }

        // ---- issue all 16 LDS reads, then interpolate ----
        uint32_t e[2][8];
#pragma unroll
        for (int p = 0; p < 2; ++p)
#pragma unroll
            for (int cc = 0; cc < 8; ++cc)
                e[p][cc] = ltab[idx[p][cc]];

        f32x2 r[2];
#pragma unroll
        for (int p = 0; p < 2; ++p) {
            float acc_x = 0.0f, acc_y = 0.0f;
#pragma unroll
            for (int cc = 0; cc < 8; ++cc) {
                __half2 h = *reinterpret_cast<__half2*>(&e[p][cc]);
                acc_x = fmaf(w[p][cc], __low2float(h),  acc_x);
                acc_y = fmaf(w[p][cc], __high2float(h), acc_y);
            }
            r[p].x = acc_x; r[p].y = acc_y;
        }

        out[(size_t)nn[0] * kL + l] = r[0];
        if (hasB) out[(size_t)nn[1] * kL + l] = r[1];
    }
}

extern "C" void kernel_launch(void* const* d_in, const int* in_sizes, int n_in,
                              void* d_out, int out_size, void* d_ws, size_t ws_size,
                              hipStream_t stream) {
    const float*  x     = (const float*)d_in[0];
    const float2* table = (const float2*)d_in[1];
    f32x2*        out   = (f32x2*)d_out;

    int n_points = in_sizes[0] / 3;                  // (N,3) flat
    int chunk_sz = (n_points + kNC - 1) / kNC;       // 31250 for N=500000
    int blocks   = kL * kNC;                         // 256 = 1 per CU

    hashgrid_fwd<<<blocks, kBT, 0, stream>>>(x, table, out, n_points, chunk_sz);
}